// Round 18
// baseline (97.402 us; speedup 1.0000x reference)
//
#include <hip/hip_runtime.h>
#include <cstddef>

// Block-cooperative MFMA MixModel, 32 rows/tile (R18 = R13 at 8 waves/block):
// R13's exact data paths/layouts/formulas; per-wave column ownership halved
// (16 GEMM1 cols, 16 GEMM2 cols) so 512-thread blocks fit 64 VGPR ->
// 4 blocks/CU x 8 waves = 32 waves/CU occupancy cap (R13: 16).
//   GEMM1 SWAPPED (R13-verified): h[row=ln][4k] -> tanh_pade -> cvt_pk -> b64.
//   GEMM2 UNSWAPPED (R13-verified): h_sh [row][k] b128 reads, 8 MFMA/wave,
//     scalar f32 c2 writes, quad-interleaved c2s [32][148].
//   Epilogue phase (R13-verified): 576 pair-items, f32x4 c2 reads, float2 out.
//   LDS 34816 B; __launch_bounds__(512,8) caps VGPR at 64 (tripwire: FETCH).

typedef __attribute__((ext_vector_type(8))) __bf16 bf16x8;
typedef __attribute__((ext_vector_type(8))) short short8;
typedef __attribute__((ext_vector_type(4))) float f32x4;

__device__ __forceinline__ unsigned short f2bf(float f) {
    unsigned int u = __float_as_uint(f);
    unsigned int r = (u + 0x7FFFu + ((u >> 16) & 1u)) >> 16;
    return (unsigned short)r;
}

__device__ __forceinline__ unsigned int cvt_pk_bf16(float lo, float hi) {
    unsigned int r;
    asm("v_cvt_pk_bf16_f32 %0, %1, %2" : "=v"(r) : "v"(lo), "v"(hi));
    return r;
}

// --- mfma wrapper: tolerate either V8bf16 or V8i16 builtin signature ---
template <typename A>
__device__ __forceinline__ auto mfma_try(A a, A b, f32x4 c, int)
    -> decltype(__builtin_amdgcn_mfma_f32_16x16x32_bf16(a, b, c, 0, 0, 0)) {
    return __builtin_amdgcn_mfma_f32_16x16x32_bf16(a, b, c, 0, 0, 0);
}
template <typename A>
__device__ __forceinline__ f32x4 mfma_try(A a, A b, f32x4 c, long) {
    return __builtin_amdgcn_mfma_f32_16x16x32_bf16(
        __builtin_bit_cast(short8, a), __builtin_bit_cast(short8, b), c, 0, 0, 0);
}
__device__ __forceinline__ f32x4 mfma_bf16(short8 a, short8 b, f32x4 c) {
    return mfma_try(__builtin_bit_cast(bf16x8, a), __builtin_bit_cast(bf16x8, b), c, 0);
}

__device__ __forceinline__ float tanh_pade(float x) {
    const float t = fminf(fmaxf(x, -3.0f), 3.0f);
    const float s = t * t;
    return __fdividef(t * (27.0f + s), fmaf(9.0f, s, 27.0f));
}

__global__ __launch_bounds__(512, 8) void mixmodel_mfma18(
    const float* __restrict__ u,      // N*36
    const float* __restrict__ reg1,   // 6
    const float* __restrict__ reg2,   // 4
    const float* __restrict__ W1,     // 18*128
    const float* __restrict__ b1,     // 128
    const float* __restrict__ W2a,    // 128*54
    const float* __restrict__ b2a,    // 54
    const float* __restrict__ W2b,    // 128*72
    const float* __restrict__ b2b,    // 72
    float* __restrict__ out,          // N*36
    int N, int ntiles)
{
    __shared__ __align__(16) float          u_ext[32 * 40];   // 5120 B
    __shared__ __align__(16) unsigned short h_sh[32 * 136];   // 8704 B (verified layout)
    __shared__ __align__(16) unsigned short u_bf[32 * 32];    // 2048 B
    __shared__ __align__(16) float          c2s[32 * 148];    // 18944 B (R13-verified)
    // total = 34816 B -> 4 blocks/CU; x8 waves = 32 waves/CU cap

    const int tid = threadIdx.x;
    const int wid = tid >> 6;        // 0..7
    const int l   = tid & 63;
    const int ln  = l & 15;
    const int lg  = l >> 4;
    const int nb  = wid * 16;        // this wave's 16-column base (both GEMMs)

    // ---- zero u_bf (512 uints, one per thread) ----
    reinterpret_cast<unsigned int*>(u_bf)[tid] = 0u;
    __syncthreads();

    // ---- GEMM1 weights (swapped; R13-verified, 1 t-tile/wave) ----
    short8 b1f;
    f32x4 bias1v;
    {
        const int n = nb + ln;
        short8 v;
#pragma unroll
        for (int j = 0; j < 8; ++j) {
            const int k = lg * 8 + j;
            const float w = (k < 18) ? W1[k * 128 + n] : 0.0f;
            v[j] = (short)f2bf(w);
        }
        b1f = v;
        bias1v = *reinterpret_cast<const f32x4*>(&b1[nb + lg * 4]);
    }

    // ---- GEMM2 weights (unswapped, R13 54-offset map; 1 t-tile/wave) ----
    short8 b2f[4];
    float bias2;
    int c2idx;
    {
        const int n = nb + ln;
        bias2 = (n < 54) ? b2a[n] : (n < 126 ? b2b[n - 54] : 0.0f);
        if (n < 54)       c2idx = (n / 3) * 8 + (n % 3);
        else if (n < 126) { const int m = n - 54; c2idx = (m >> 2) * 8 + 4 + (m & 3); }
        else              c2idx = 3;  // dump slot, never read
#pragma unroll
        for (int kk = 0; kk < 4; ++kk) {
            short8 w2;
#pragma unroll
            for (int j = 0; j < 8; ++j) {
                const int k = kk * 32 + lg * 8 + j;
                float w;
                if (n < 54)       w = W2a[k * 54 + n];
                else if (n < 126) w = W2b[k * 72 + (n - 54)];
                else              w = 0.0f;
                w2[j] = (short)f2bf(w);
            }
            b2f[kk] = w2;
        }
    }

    // ---- regression coefficients (wave-uniform -> SGPR) ----
    const float r10 = reg1[0], r11 = reg1[1], r12 = reg1[2];
    const float r13 = reg1[3], r14 = reg1[4], r15 = reg1[5];
    const float r20 = reg2[0], r21 = reg2[1], r22 = reg2[2], r23 = reg2[3];

    const float4* ug = reinterpret_cast<const float4*>(u);
    const long fmax4 = (long)N * 9 - 1;
    const int gs = gridDim.x;

    // ---- staging maps: 288 float4 (tid<288); 64 halo float2 (tid>=448) ----
    const int row0 = tid / 9, c0 = tid - row0 * 9;         // valid when tid<288
    const int hrow = (tid - 448) >> 1, hside = tid & 1;    // valid when tid>=448

    float4 pf0; float2 pfh;
    {
        const int r0 = blockIdx.x * 32;
        if (tid < 288) {
            long g0 = (long)r0 * 9 + tid; if (g0 > fmax4) g0 = fmax4;
            pf0 = ug[g0];
        }
        if (tid >= 448) {
            int rr = r0 + hrow; if (rr > N - 1) rr = N - 1;
            pfh = *reinterpret_cast<const float2*>(u + (size_t)rr * 36 + (hside ? 0 : 34));
        }
    }

    for (int tile = blockIdx.x; tile < ntiles; tile += gs) {
        // ---- stage u_ext / u_bf (cvt_pk); prefetch next (R13-verified maps) ----
        {
            if (tid < 288) {
                float* dst = &u_ext[row0 * 40 + 2 + c0 * 4];
                reinterpret_cast<float2*>(dst)[0] = make_float2(pf0.x, pf0.y);
                reinterpret_cast<float2*>(dst)[1] = make_float2(pf0.z, pf0.w);
                reinterpret_cast<unsigned int*>(u_bf)[row0 * 16 + c0] =
                    cvt_pk_bf16(pf0.x, pf0.z);
            }
            if (tid >= 448)
                *reinterpret_cast<float2*>(&u_ext[hrow * 40 + (hside ? 38 : 0)]) = pfh;

            if (tile + gs < ntiles) {
                const int r0n = (tile + gs) * 32;
                if (tid < 288) {
                    long g0 = (long)r0n * 9 + tid; if (g0 > fmax4) g0 = fmax4;
                    pf0 = ug[g0];
                }
                if (tid >= 448) {
                    int rr = r0n + hrow; if (rr > N - 1) rr = N - 1;
                    pfh = *reinterpret_cast<const float2*>(u + (size_t)rr * 36 + (hside ? 0 : 34));
                }
            }
        }
        __syncthreads();  // bar1: u ready

        // ---- GEMM1 SWAPPED (R13-verified; 1 t-tile): 2 MFMA/wave ----
#pragma unroll
        for (int rb = 0; rb < 2; ++rb) {
            const short8 a1 = *reinterpret_cast<const short8*>(
                &u_bf[(rb * 16 + ln) * 32 + lg * 8]);
            const f32x4 h4 = mfma_bf16(b1f, a1, bias1v);   // SWAPPED -> h^T
            const unsigned int p0 =
                cvt_pk_bf16(tanh_pade(h4[0]), tanh_pade(h4[1]));
            const unsigned int p1 =
                cvt_pk_bf16(tanh_pade(h4[2]), tanh_pade(h4[3]));
            *reinterpret_cast<uint2*>(
                &h_sh[(rb * 16 + ln) * 136 + nb + lg * 4]) = make_uint2(p0, p1);
        }
        __syncthreads();  // bar2: h ready

        // ---- GEMM2 UNSWAPPED (R13-verified; 1 t-tile): 8 MFMA/wave ----
        f32x4 acc2[2];
#pragma unroll
        for (int rb = 0; rb < 2; ++rb) acc2[rb] = (f32x4)bias2;

#pragma unroll
        for (int rb = 0; rb < 2; ++rb) {
            const int arow = rb * 16 + ln;
#pragma unroll
            for (int kk = 0; kk < 4; ++kk) {
                const short8 a2 = *reinterpret_cast<const short8*>(
                    &h_sh[arow * 136 + kk * 32 + lg * 8]);
                acc2[rb] = mfma_bf16(a2, b2f[kk], acc2[rb]);
            }
        }

        // ---- C2 -> LDS float (R13-verified addressing, stride 148) ----
#pragma unroll
        for (int rb = 0; rb < 2; ++rb)
#pragma unroll
            for (int r = 0; r < 4; ++r)
                c2s[(rb * 16 + lg * 4 + r) * 148 + c2idx] = acc2[rb][r];
        __syncthreads();  // bar3: c2 ready

        // ---- epilogue (R13-verified): 576 items over 512 threads ----
        const int r0 = tile * 32;
#pragma unroll
        for (int s = 0; s < 2; ++s) {
            const int w = s * 512 + tid;
            if (w < 576) {
                const int row = w / 18;
                const int i   = w - row * 18;
                const int rg  = r0 + row;

                const float2 v0 = *reinterpret_cast<const float2*>(&u_ext[row * 40 + 2 * i]);
                const float2 v1 = *reinterpret_cast<const float2*>(&u_ext[row * 40 + 2 * i + 2]);
                const float2 v2 = *reinterpret_cast<const float2*>(&u_ext[row * 40 + 2 * i + 4]);
                const f32x4  q0 = *reinterpret_cast<const f32x4*>(&c2s[row * 148 + 8 * i]);
                const f32x4  q1 = *reinterpret_cast<const f32x4*>(&c2s[row * 148 + 8 * i + 4]);

                const float um2 = v0.x, uA = v0.y;
                const float ue  = v1.x, uo = v1.y;
                const float up2 = v2.x, uC = v2.y;

                const float oe = q0[0] + q0[1] * uA + q0[2] * uo;
                const float oo = q1[0] + q1[1] * uA + q1[2] * uo + q1[3] * uC;

                float re = r10;
                re = fmaf(r11, ue,       re);
                re = fmaf(r12, uo,       re);
                re = fmaf(r13, um2 * uA, re);
                re = fmaf(r14, uA * up2, re);
                re = fmaf(r15, ue * uo,  re);

                float ro = r20;
                ro = fmaf(r21, uo,       ro);
                ro = fmaf(r22, uA * ue,  ro);
                ro = fmaf(r23, ue * up2, ro);

                if (rg < N)
                    *reinterpret_cast<float2*>(out + (size_t)rg * 36 + 2 * i) =
                        make_float2(oe + re, oo + ro);
            }
        }
        __syncthreads();  // bar4: buffers free for next staging
    }
}

extern "C" void kernel_launch(void* const* d_in, const int* in_sizes, int n_in,
                              void* d_out, int out_size, void* d_ws, size_t ws_size,
                              hipStream_t stream) {
    // d_in order: t, u, reg1, reg2, W1, b1, W2a, b2a, W2b, b2b
    const float* u    = (const float*)d_in[1];
    const float* reg1 = (const float*)d_in[2];
    const float* reg2 = (const float*)d_in[3];
    const float* W1   = (const float*)d_in[4];
    const float* b1   = (const float*)d_in[5];
    const float* W2a  = (const float*)d_in[6];
    const float* b2a  = (const float*)d_in[7];
    const float* W2b  = (const float*)d_in[8];
    const float* b2b  = (const float*)d_in[9];
    float* out = (float*)d_out;

    const int N = in_sizes[1] / 36;
    const int ntiles = (N + 31) / 32;
    int grid = ntiles < 1024 ? ntiles : 1024;   // 4 blocks/CU by LDS
    if (grid < 1) grid = 1;
    mixmodel_mfma18<<<grid, 512, 0, stream>>>(u, reg1, reg2, W1, b1,
                                              W2a, b2a, W2b, b2b, out, N, ntiles);
}

// Round 19
// 88.144 us; speedup vs baseline: 1.1050x; 1.1050x over previous
//
#include <hip/hip_runtime.h>
#include <cstddef>

// Block-cooperative MFMA MixModel, 32 rows/tile (R19 = R18 at launch_bounds(512,4)):
// R18's exact structure (R13 data paths at 8 waves/block, 16 cols/wave), but the
// register cap relaxed 8->4 waves/EU: R18's (512,8) forced <=64 regs -> VGPR 32 +
// spill (FETCH +45MB, WRITE +100MB). (512,4) allows 128; kernel needs ~66-70.
// Resident: threads 2048/CU -> 4 blocks; LDS 34.8KB -> 4 blocks; VGPR ~66-85 ->
// 6-7 waves/SIMD -> 24-32 waves/CU occupancy cap (R13: 16).
//   GEMM1 SWAPPED (R13/R18-verified): h[row=ln][4k] -> tanh_pade -> cvt_pk -> b64.
//   GEMM2 UNSWAPPED (R13/R18-verified): h_sh [row][k] b128 reads, 8 MFMA/wave,
//     scalar f32 c2 writes, quad-interleaved c2s [32][148].
//   Epilogue phase (R13/R18-verified): 576 pair-items, f32x4 c2 reads, float2 out.

typedef __attribute__((ext_vector_type(8))) __bf16 bf16x8;
typedef __attribute__((ext_vector_type(8))) short short8;
typedef __attribute__((ext_vector_type(4))) float f32x4;

__device__ __forceinline__ unsigned short f2bf(float f) {
    unsigned int u = __float_as_uint(f);
    unsigned int r = (u + 0x7FFFu + ((u >> 16) & 1u)) >> 16;
    return (unsigned short)r;
}

__device__ __forceinline__ unsigned int cvt_pk_bf16(float lo, float hi) {
    unsigned int r;
    asm("v_cvt_pk_bf16_f32 %0, %1, %2" : "=v"(r) : "v"(lo), "v"(hi));
    return r;
}

// --- mfma wrapper: tolerate either V8bf16 or V8i16 builtin signature ---
template <typename A>
__device__ __forceinline__ auto mfma_try(A a, A b, f32x4 c, int)
    -> decltype(__builtin_amdgcn_mfma_f32_16x16x32_bf16(a, b, c, 0, 0, 0)) {
    return __builtin_amdgcn_mfma_f32_16x16x32_bf16(a, b, c, 0, 0, 0);
}
template <typename A>
__device__ __forceinline__ f32x4 mfma_try(A a, A b, f32x4 c, long) {
    return __builtin_amdgcn_mfma_f32_16x16x32_bf16(
        __builtin_bit_cast(short8, a), __builtin_bit_cast(short8, b), c, 0, 0, 0);
}
__device__ __forceinline__ f32x4 mfma_bf16(short8 a, short8 b, f32x4 c) {
    return mfma_try(__builtin_bit_cast(bf16x8, a), __builtin_bit_cast(bf16x8, b), c, 0);
}

__device__ __forceinline__ float tanh_pade(float x) {
    const float t = fminf(fmaxf(x, -3.0f), 3.0f);
    const float s = t * t;
    return __fdividef(t * (27.0f + s), fmaf(9.0f, s, 27.0f));
}

__global__ __launch_bounds__(512, 4) void mixmodel_mfma19(
    const float* __restrict__ u,      // N*36
    const float* __restrict__ reg1,   // 6
    const float* __restrict__ reg2,   // 4
    const float* __restrict__ W1,     // 18*128
    const float* __restrict__ b1,     // 128
    const float* __restrict__ W2a,    // 128*54
    const float* __restrict__ b2a,    // 54
    const float* __restrict__ W2b,    // 128*72
    const float* __restrict__ b2b,    // 72
    float* __restrict__ out,          // N*36
    int N, int ntiles)
{
    __shared__ __align__(16) float          u_ext[32 * 40];   // 5120 B
    __shared__ __align__(16) unsigned short h_sh[32 * 136];   // 8704 B (verified layout)
    __shared__ __align__(16) unsigned short u_bf[32 * 32];    // 2048 B
    __shared__ __align__(16) float          c2s[32 * 148];    // 18944 B (R13-verified)
    // total = 34816 B -> 4 blocks/CU by LDS; threads also cap at 4 blocks

    const int tid = threadIdx.x;
    const int wid = tid >> 6;        // 0..7
    const int l   = tid & 63;
    const int ln  = l & 15;
    const int lg  = l >> 4;
    const int nb  = wid * 16;        // this wave's 16-column base (both GEMMs)

    // ---- zero u_bf (512 uints, one per thread) ----
    reinterpret_cast<unsigned int*>(u_bf)[tid] = 0u;
    __syncthreads();

    // ---- GEMM1 weights (swapped; R13/R18-verified, 1 t-tile/wave) ----
    short8 b1f;
    f32x4 bias1v;
    {
        const int n = nb + ln;
        short8 v;
#pragma unroll
        for (int j = 0; j < 8; ++j) {
            const int k = lg * 8 + j;
            const float w = (k < 18) ? W1[k * 128 + n] : 0.0f;
            v[j] = (short)f2bf(w);
        }
        b1f = v;
        bias1v = *reinterpret_cast<const f32x4*>(&b1[nb + lg * 4]);
    }

    // ---- GEMM2 weights (unswapped, R13 54-offset map; 1 t-tile/wave) ----
    short8 b2f[4];
    float bias2;
    int c2idx;
    {
        const int n = nb + ln;
        bias2 = (n < 54) ? b2a[n] : (n < 126 ? b2b[n - 54] : 0.0f);
        if (n < 54)       c2idx = (n / 3) * 8 + (n % 3);
        else if (n < 126) { const int m = n - 54; c2idx = (m >> 2) * 8 + 4 + (m & 3); }
        else              c2idx = 3;  // dump slot, never read
#pragma unroll
        for (int kk = 0; kk < 4; ++kk) {
            short8 w2;
#pragma unroll
            for (int j = 0; j < 8; ++j) {
                const int k = kk * 32 + lg * 8 + j;
                float w;
                if (n < 54)       w = W2a[k * 54 + n];
                else if (n < 126) w = W2b[k * 72 + (n - 54)];
                else              w = 0.0f;
                w2[j] = (short)f2bf(w);
            }
            b2f[kk] = w2;
        }
    }

    // ---- regression coefficients (wave-uniform -> SGPR) ----
    const float r10 = reg1[0], r11 = reg1[1], r12 = reg1[2];
    const float r13 = reg1[3], r14 = reg1[4], r15 = reg1[5];
    const float r20 = reg2[0], r21 = reg2[1], r22 = reg2[2], r23 = reg2[3];

    const float4* ug = reinterpret_cast<const float4*>(u);
    const long fmax4 = (long)N * 9 - 1;
    const int gs = gridDim.x;

    // ---- staging maps: 288 float4 (tid<288); 64 halo float2 (tid>=448) ----
    const int row0 = tid / 9, c0 = tid - row0 * 9;         // valid when tid<288
    const int hrow = (tid - 448) >> 1, hside = tid & 1;    // valid when tid>=448

    float4 pf0; float2 pfh;
    {
        const int r0 = blockIdx.x * 32;
        if (tid < 288) {
            long g0 = (long)r0 * 9 + tid; if (g0 > fmax4) g0 = fmax4;
            pf0 = ug[g0];
        }
        if (tid >= 448) {
            int rr = r0 + hrow; if (rr > N - 1) rr = N - 1;
            pfh = *reinterpret_cast<const float2*>(u + (size_t)rr * 36 + (hside ? 0 : 34));
        }
    }

    for (int tile = blockIdx.x; tile < ntiles; tile += gs) {
        // ---- stage u_ext / u_bf (cvt_pk); prefetch next (R13/R18-verified) ----
        {
            if (tid < 288) {
                float* dst = &u_ext[row0 * 40 + 2 + c0 * 4];
                reinterpret_cast<float2*>(dst)[0] = make_float2(pf0.x, pf0.y);
                reinterpret_cast<float2*>(dst)[1] = make_float2(pf0.z, pf0.w);
                reinterpret_cast<unsigned int*>(u_bf)[row0 * 16 + c0] =
                    cvt_pk_bf16(pf0.x, pf0.z);
            }
            if (tid >= 448)
                *reinterpret_cast<float2*>(&u_ext[hrow * 40 + (hside ? 38 : 0)]) = pfh;

            if (tile + gs < ntiles) {
                const int r0n = (tile + gs) * 32;
                if (tid < 288) {
                    long g0 = (long)r0n * 9 + tid; if (g0 > fmax4) g0 = fmax4;
                    pf0 = ug[g0];
                }
                if (tid >= 448) {
                    int rr = r0n + hrow; if (rr > N - 1) rr = N - 1;
                    pfh = *reinterpret_cast<const float2*>(u + (size_t)rr * 36 + (hside ? 0 : 34));
                }
            }
        }
        __syncthreads();  // bar1: u ready

        // ---- GEMM1 SWAPPED (verified; 1 t-tile): 2 MFMA/wave ----
#pragma unroll
        for (int rb = 0; rb < 2; ++rb) {
            const short8 a1 = *reinterpret_cast<const short8*>(
                &u_bf[(rb * 16 + ln) * 32 + lg * 8]);
            const f32x4 h4 = mfma_bf16(b1f, a1, bias1v);   // SWAPPED -> h^T
            const unsigned int p0 =
                cvt_pk_bf16(tanh_pade(h4[0]), tanh_pade(h4[1]));
            const unsigned int p1 =
                cvt_pk_bf16(tanh_pade(h4[2]), tanh_pade(h4[3]));
            *reinterpret_cast<uint2*>(
                &h_sh[(rb * 16 + ln) * 136 + nb + lg * 4]) = make_uint2(p0, p1);
        }
        __syncthreads();  // bar2: h ready

        // ---- GEMM2 UNSWAPPED (verified; 1 t-tile): 8 MFMA/wave ----
        f32x4 acc2[2];
#pragma unroll
        for (int rb = 0; rb < 2; ++rb) acc2[rb] = (f32x4)bias2;

#pragma unroll
        for (int rb = 0; rb < 2; ++rb) {
            const int arow = rb * 16 + ln;
#pragma unroll
            for (int kk = 0; kk < 4; ++kk) {
                const short8 a2 = *reinterpret_cast<const short8*>(
                    &h_sh[arow * 136 + kk * 32 + lg * 8]);
                acc2[rb] = mfma_bf16(a2, b2f[kk], acc2[rb]);
            }
        }

        // ---- C2 -> LDS float (verified addressing, stride 148) ----
#pragma unroll
        for (int rb = 0; rb < 2; ++rb)
#pragma unroll
            for (int r = 0; r < 4; ++r)
                c2s[(rb * 16 + lg * 4 + r) * 148 + c2idx] = acc2[rb][r];
        __syncthreads();  // bar3: c2 ready

        // ---- epilogue (verified): 576 items over 512 threads ----
        const int r0 = tile * 32;
#pragma unroll
        for (int s = 0; s < 2; ++s) {
            const int w = s * 512 + tid;
            if (w < 576) {
                const int row = w / 18;
                const int i   = w - row * 18;
                const int rg  = r0 + row;

                const float2 v0 = *reinterpret_cast<const float2*>(&u_ext[row * 40 + 2 * i]);
                const float2 v1 = *reinterpret_cast<const float2*>(&u_ext[row * 40 + 2 * i + 2]);
                const float2 v2 = *reinterpret_cast<const float2*>(&u_ext[row * 40 + 2 * i + 4]);
                const f32x4  q0 = *reinterpret_cast<const f32x4*>(&c2s[row * 148 + 8 * i]);
                const f32x4  q1 = *reinterpret_cast<const f32x4*>(&c2s[row * 148 + 8 * i + 4]);

                const float um2 = v0.x, uA = v0.y;
                const float ue  = v1.x, uo = v1.y;
                const float up2 = v2.x, uC = v2.y;

                const float oe = q0[0] + q0[1] * uA + q0[2] * uo;
                const float oo = q1[0] + q1[1] * uA + q1[2] * uo + q1[3] * uC;

                float re = r10;
                re = fmaf(r11, ue,       re);
                re = fmaf(r12, uo,       re);
                re = fmaf(r13, um2 * uA, re);
                re = fmaf(r14, uA * up2, re);
                re = fmaf(r15, ue * uo,  re);

                float ro = r20;
                ro = fmaf(r21, uo,       ro);
                ro = fmaf(r22, uA * ue,  ro);
                ro = fmaf(r23, ue * up2, ro);

                if (rg < N)
                    *reinterpret_cast<float2*>(out + (size_t)rg * 36 + 2 * i) =
                        make_float2(oe + re, oo + ro);
            }
        }
        __syncthreads();  // bar4: buffers free for next staging
    }
}

extern "C" void kernel_launch(void* const* d_in, const int* in_sizes, int n_in,
                              void* d_out, int out_size, void* d_ws, size_t ws_size,
                              hipStream_t stream) {
    // d_in order: t, u, reg1, reg2, W1, b1, W2a, b2a, W2b, b2b
    const float* u    = (const float*)d_in[1];
    const float* reg1 = (const float*)d_in[2];
    const float* reg2 = (const float*)d_in[3];
    const float* W1   = (const float*)d_in[4];
    const float* b1   = (const float*)d_in[5];
    const float* W2a  = (const float*)d_in[6];
    const float* b2a  = (const float*)d_in[7];
    const float* W2b  = (const float*)d_in[8];
    const float* b2b  = (const float*)d_in[9];
    float* out = (float*)d_out;

    const int N = in_sizes[1] / 36;
    const int ntiles = (N + 31) / 32;
    int grid = ntiles < 1024 ? ntiles : 1024;
    if (grid < 1) grid = 1;
    mixmodel_mfma19<<<grid, 512, 0, stream>>>(u, reg1, reg2, W1, b1,
                                              W2a, b2a, W2b, b2b, out, N, ntiles);
}

// Round 20
// 77.764 us; speedup vs baseline: 1.2525x; 1.1335x over previous
//
#include <hip/hip_runtime.h>
#include <cstddef>

// Block-cooperative MFMA MixModel, 32 rows/tile (R20 = R13 + bar4 removal):
// R13 byte-identical data paths; u_ext double-buffered (+5KB) which makes the
// 4th barrier provably deletable:
//   after bar3, pre-bar1 window touches: u_ext (epi reads || stage writes ->
//   RACE -> double-buffer), u_bf (stage writes; last read G1(k) fenced by
//   bar2<bar3 -> safe), c2s (epi reads; next write G2(k+1) fenced by
//   bar2(k+1) -> safe), h_sh (untouched). 3 barriers/tile; staging+prefetch
//   overlaps the epilogue.
//   GEMM1 SWAPPED (R13-verified): h[row=ln][4k] -> tanh_pade -> cvt_pk -> b64.
//   GEMM2 UNSWAPPED (R13-verified): h_sh [row][k] b128 reads, 16 MFMA,
//     scalar f32 c2 writes, quad-interleaved c2s [32][148].
//   Epilogue (R13-verified): 576 pair-items, f32x4 c2 reads, float2 out.
//   LDS 39936 B -> 4 blocks/CU.

typedef __attribute__((ext_vector_type(8))) __bf16 bf16x8;
typedef __attribute__((ext_vector_type(8))) short short8;
typedef __attribute__((ext_vector_type(4))) float f32x4;

__device__ __forceinline__ unsigned short f2bf(float f) {
    unsigned int u = __float_as_uint(f);
    unsigned int r = (u + 0x7FFFu + ((u >> 16) & 1u)) >> 16;
    return (unsigned short)r;
}

__device__ __forceinline__ unsigned int cvt_pk_bf16(float lo, float hi) {
    unsigned int r;
    asm("v_cvt_pk_bf16_f32 %0, %1, %2" : "=v"(r) : "v"(lo), "v"(hi));
    return r;
}

// --- mfma wrapper: tolerate either V8bf16 or V8i16 builtin signature ---
template <typename A>
__device__ __forceinline__ auto mfma_try(A a, A b, f32x4 c, int)
    -> decltype(__builtin_amdgcn_mfma_f32_16x16x32_bf16(a, b, c, 0, 0, 0)) {
    return __builtin_amdgcn_mfma_f32_16x16x32_bf16(a, b, c, 0, 0, 0);
}
template <typename A>
__device__ __forceinline__ f32x4 mfma_try(A a, A b, f32x4 c, long) {
    return __builtin_amdgcn_mfma_f32_16x16x32_bf16(
        __builtin_bit_cast(short8, a), __builtin_bit_cast(short8, b), c, 0, 0, 0);
}
__device__ __forceinline__ f32x4 mfma_bf16(short8 a, short8 b, f32x4 c) {
    return mfma_try(__builtin_bit_cast(bf16x8, a), __builtin_bit_cast(bf16x8, b), c, 0);
}

__device__ __forceinline__ float tanh_pade(float x) {
    const float t = fminf(fmaxf(x, -3.0f), 3.0f);
    const float s = t * t;
    return __fdividef(t * (27.0f + s), fmaf(9.0f, s, 27.0f));
}

__global__ __launch_bounds__(256, 4) void mixmodel_mfma20(
    const float* __restrict__ u,      // N*36
    const float* __restrict__ reg1,   // 6
    const float* __restrict__ reg2,   // 4
    const float* __restrict__ W1,     // 18*128
    const float* __restrict__ b1,     // 128
    const float* __restrict__ W2a,    // 128*54
    const float* __restrict__ b2a,    // 54
    const float* __restrict__ W2b,    // 128*72
    const float* __restrict__ b2b,    // 72
    float* __restrict__ out,          // N*36
    int N, int ntiles)
{
    __shared__ __align__(16) float          u_ext[2][32 * 40]; // 10240 B (double-buffered)
    __shared__ __align__(16) unsigned short h_sh[32 * 136];    // 8704 B (verified layout)
    __shared__ __align__(16) unsigned short u_bf[32 * 32];     // 2048 B (single: fenced by bar3)
    __shared__ __align__(16) float          c2s[32 * 148];     // 18944 B (R13-verified)
    // total = 39936 B -> 4 blocks/CU

    const int tid = threadIdx.x;
    const int wid = tid >> 6;
    const int l   = tid & 63;
    const int ln  = l & 15;
    const int lg  = l >> 4;
    const int nb  = wid * 32;

    reinterpret_cast<unsigned int*>(u_bf)[tid]       = 0u;
    reinterpret_cast<unsigned int*>(u_bf)[tid + 256] = 0u;
    __syncthreads();

    // ---- resident weight fragments (R13-verified data + maps): 40 VGPRs ----
    short8 b1f[2];
    short8 b2f[2][4];
    f32x4 bias1v[2];            // per-reg bias for swapped GEMM1
    float bias2[2];             // per-lane bias for unswapped GEMM2
    int c2idx[2];               // quad-interleaved in-row index (max 143)
#pragma unroll
    for (int t = 0; t < 2; ++t) {
        const int n = nb + t * 16 + ln;
        short8 v;
#pragma unroll
        for (int j = 0; j < 8; ++j) {
            const int k = lg * 8 + j;
            const float w = (k < 18) ? W1[k * 128 + n] : 0.0f;
            v[j] = (short)f2bf(w);
        }
        b1f[t] = v;
        bias1v[t] = *reinterpret_cast<const f32x4*>(&b1[nb + t * 16 + lg * 4]);
        bias2[t] = (n < 54) ? b2a[n] : (n < 126 ? b2b[n - 54] : 0.0f);
        if (n < 54)       c2idx[t] = (n / 3) * 8 + (n % 3);
        else if (n < 126) { const int m = n - 54; c2idx[t] = (m >> 2) * 8 + 4 + (m & 3); }
        else              c2idx[t] = 3;  // dump slot, never read
#pragma unroll
        for (int kk = 0; kk < 4; ++kk) {
            short8 w2;
#pragma unroll
            for (int j = 0; j < 8; ++j) {
                const int k = kk * 32 + lg * 8 + j;
                float w;
                if (n < 54)       w = W2a[k * 54 + n];
                else if (n < 126) w = W2b[k * 72 + (n - 54)];
                else              w = 0.0f;
                w2[j] = (short)f2bf(w);
            }
            b2f[t][kk] = w2;
        }
    }

    // ---- regression coefficients (wave-uniform -> SGPR) ----
    const float r10 = reg1[0], r11 = reg1[1], r12 = reg1[2];
    const float r13 = reg1[3], r14 = reg1[4], r15 = reg1[5];
    const float r20 = reg2[0], r21 = reg2[1], r22 = reg2[2], r23 = reg2[3];

    const float4* ug = reinterpret_cast<const float4*>(u);
    const long fmax4 = (long)N * 9 - 1;
    const int gs = gridDim.x;

    // ---- staging maps (R8-verified) ----
    const int row0 = tid / 9,          c0 = tid - row0 * 9;
    const int row1 = (256 + tid) / 9,  c1s = (256 + tid) - row1 * 9;
    const int hrow = (tid - 192) >> 1, hside = tid & 1;

    float4 pf0, pf1; float2 pfh;
    {
        const int r0 = blockIdx.x * 32;
        long g0 = (long)r0 * 9 + tid; if (g0 > fmax4) g0 = fmax4;
        pf0 = ug[g0];
        if (tid < 32) {
            long g1 = (long)r0 * 9 + 256 + tid; if (g1 > fmax4) g1 = fmax4;
            pf1 = ug[g1];
        }
        if (tid >= 192) {
            int rr = r0 + hrow; if (rr > N - 1) rr = N - 1;
            pfh = *reinterpret_cast<const float2*>(u + (size_t)rr * 36 + (hside ? 0 : 34));
        }
    }

    int b = 0;
    for (int tile = blockIdx.x; tile < ntiles; tile += gs) {
        // ---- stage u_ext[b] / u_bf (cvt_pk); prefetch next (R13-verified) ----
        {
            float* ue_b = u_ext[b];
            float* dst = &ue_b[row0 * 40 + 2 + c0 * 4];
            reinterpret_cast<float2*>(dst)[0] = make_float2(pf0.x, pf0.y);
            reinterpret_cast<float2*>(dst)[1] = make_float2(pf0.z, pf0.w);
            reinterpret_cast<unsigned int*>(u_bf)[row0 * 16 + c0] =
                cvt_pk_bf16(pf0.x, pf0.z);
            if (tid < 32) {
                float* dst1 = &ue_b[row1 * 40 + 2 + c1s * 4];
                reinterpret_cast<float2*>(dst1)[0] = make_float2(pf1.x, pf1.y);
                reinterpret_cast<float2*>(dst1)[1] = make_float2(pf1.z, pf1.w);
                reinterpret_cast<unsigned int*>(u_bf)[row1 * 16 + c1s] =
                    cvt_pk_bf16(pf1.x, pf1.z);
            }
            if (tid >= 192)
                *reinterpret_cast<float2*>(&ue_b[hrow * 40 + (hside ? 38 : 0)]) = pfh;

            if (tile + gs < ntiles) {
                const int r0n = (tile + gs) * 32;
                long g0 = (long)r0n * 9 + tid; if (g0 > fmax4) g0 = fmax4;
                pf0 = ug[g0];
                if (tid < 32) {
                    long g1 = (long)r0n * 9 + 256 + tid; if (g1 > fmax4) g1 = fmax4;
                    pf1 = ug[g1];
                }
                if (tid >= 192) {
                    int rr = r0n + hrow; if (rr > N - 1) rr = N - 1;
                    pfh = *reinterpret_cast<const float2*>(u + (size_t)rr * 36 + (hside ? 0 : 34));
                }
            }
        }
        __syncthreads();  // bar1: u ready

        // ---- GEMM1 SWAPPED (R13-verified) ----
#pragma unroll
        for (int rb = 0; rb < 2; ++rb) {
            const short8 a1 = *reinterpret_cast<const short8*>(
                &u_bf[(rb * 16 + ln) * 32 + lg * 8]);
#pragma unroll
            for (int t = 0; t < 2; ++t) {
                const f32x4 h4 = mfma_bf16(b1f[t], a1, bias1v[t]);   // SWAPPED -> h^T
                const unsigned int p0 =
                    cvt_pk_bf16(tanh_pade(h4[0]), tanh_pade(h4[1]));
                const unsigned int p1 =
                    cvt_pk_bf16(tanh_pade(h4[2]), tanh_pade(h4[3]));
                *reinterpret_cast<uint2*>(
                    &h_sh[(rb * 16 + ln) * 136 + nb + t * 16 + lg * 4]) =
                    make_uint2(p0, p1);
            }
        }
        __syncthreads();  // bar2: h ready

        // ---- GEMM2 UNSWAPPED (R13-verified): b128 reads, 16 MFMA ----
        f32x4 acc2[2][2];
#pragma unroll
        for (int rb = 0; rb < 2; ++rb)
#pragma unroll
            for (int t = 0; t < 2; ++t) acc2[rb][t] = (f32x4)bias2[t];

#pragma unroll
        for (int rb = 0; rb < 2; ++rb) {
            const int arow = rb * 16 + ln;
#pragma unroll
            for (int kk = 0; kk < 4; ++kk) {
                const short8 a2 = *reinterpret_cast<const short8*>(
                    &h_sh[arow * 136 + kk * 32 + lg * 8]);
#pragma unroll
                for (int t = 0; t < 2; ++t)
                    acc2[rb][t] = mfma_bf16(a2, b2f[t][kk], acc2[rb][t]);
            }
        }

        // ---- C2 -> LDS float (R13-verified addressing, stride 148) ----
#pragma unroll
        for (int rb = 0; rb < 2; ++rb)
#pragma unroll
            for (int t = 0; t < 2; ++t)
#pragma unroll
                for (int r = 0; r < 4; ++r)
                    c2s[(rb * 16 + lg * 4 + r) * 148 + c2idx[t]] = acc2[rb][t][r];
        __syncthreads();  // bar3: c2 ready

        // ---- epilogue (R13-verified, stride 148); NO bar4 after (u_ext dbuf) ----
        const int r0 = tile * 32;
        const float* ue_b = u_ext[b];
#pragma unroll
        for (int s = 0; s < 3; ++s) {
            const int w = s * 256 + tid;
            if (w < 576) {
                const int row = w / 18;
                const int i   = w - row * 18;
                const int rg  = r0 + row;

                const float2 v0 = *reinterpret_cast<const float2*>(&ue_b[row * 40 + 2 * i]);
                const float2 v1 = *reinterpret_cast<const float2*>(&ue_b[row * 40 + 2 * i + 2]);
                const float2 v2 = *reinterpret_cast<const float2*>(&ue_b[row * 40 + 2 * i + 4]);
                const f32x4  q0 = *reinterpret_cast<const f32x4*>(&c2s[row * 148 + 8 * i]);
                const f32x4  q1 = *reinterpret_cast<const f32x4*>(&c2s[row * 148 + 8 * i + 4]);

                const float um2 = v0.x, uA = v0.y;
                const float ue  = v1.x, uo = v1.y;
                const float up2 = v2.x, uC = v2.y;

                const float oe = q0[0] + q0[1] * uA + q0[2] * uo;
                const float oo = q1[0] + q1[1] * uA + q1[2] * uo + q1[3] * uC;

                float re = r10;
                re = fmaf(r11, ue,       re);
                re = fmaf(r12, uo,       re);
                re = fmaf(r13, um2 * uA, re);
                re = fmaf(r14, uA * up2, re);
                re = fmaf(r15, ue * uo,  re);

                float ro = r20;
                ro = fmaf(r21, uo,       ro);
                ro = fmaf(r22, uA * ue,  ro);
                ro = fmaf(r23, ue * up2, ro);

                if (rg < N)
                    *reinterpret_cast<float2*>(out + (size_t)rg * 36 + 2 * i) =
                        make_float2(oe + re, oo + ro);
            }
        }
        b ^= 1;   // staging of tile k+1 writes the other u_ext buffer
    }
}

extern "C" void kernel_launch(void* const* d_in, const int* in_sizes, int n_in,
                              void* d_out, int out_size, void* d_ws, size_t ws_size,
                              hipStream_t stream) {
    // d_in order: t, u, reg1, reg2, W1, b1, W2a, b2a, W2b, b2b
    const float* u    = (const float*)d_in[1];
    const float* reg1 = (const float*)d_in[2];
    const float* reg2 = (const float*)d_in[3];
    const float* W1   = (const float*)d_in[4];
    const float* b1   = (const float*)d_in[5];
    const float* W2a  = (const float*)d_in[6];
    const float* b2a  = (const float*)d_in[7];
    const float* W2b  = (const float*)d_in[8];
    const float* b2b  = (const float*)d_in[9];
    float* out = (float*)d_out;

    const int N = in_sizes[1] / 36;
    const int ntiles = (N + 31) / 32;
    int grid = ntiles < 1024 ? ntiles : 1024;
    if (grid < 1) grid = 1;
    mixmodel_mfma20<<<grid, 256, 0, stream>>>(u, reg1, reg2, W1, b1,
                                              W2a, b2a, W2b, b2b, out, N, ntiles);
}

// Round 21
// 74.981 us; speedup vs baseline: 1.2990x; 1.0371x over previous
//
#include <hip/hip_runtime.h>
#include <cstddef>

// Block-cooperative MFMA MixModel, 32 rows/tile (R21 = R13 verbatim, best-known:
// 75.5us, passed, no spill). R13 = R10 structure + three R11-verified subs
// (tanh_pade, cvt_pk h-pack, cvt_pk u_bf staging).
// Search-tree summary (all measured WORSE than this):
//   swapped-GEMM2 (R9/R11/R17), in-register epilogue (R14/15/16: VGPR spills),
//   8-wave blocks (R18/19), bar4 elision via u_ext dbuf (R20: neutral-negative).
// Regime: VALU ~56%, LDS-pipe ~50-70% (conflict tax ~10.9M), MFMA ~10% --
// instruction-issue plateau of this formulation.
//   GEMM1 SWAPPED: lane holds h[row=ln][4k] -> tanh_pade -> cvt_pk -> ds_write_b64.
//   GEMM2 UNSWAPPED: h_sh [row][k] b128 reads, 16 MFMA, scalar FLOAT c2 writes.
//   c2s float [32][148] quad-interleaved, epilogue 2x f32x4 reads.

typedef __attribute__((ext_vector_type(8))) __bf16 bf16x8;
typedef __attribute__((ext_vector_type(8))) short short8;
typedef __attribute__((ext_vector_type(4))) float f32x4;

__device__ __forceinline__ unsigned short f2bf(float f) {
    // manual RNE float->bf16 (init-time only)
    unsigned int u = __float_as_uint(f);
    unsigned int r = (u + 0x7FFFu + ((u >> 16) & 1u)) >> 16;
    return (unsigned short)r;
}

__device__ __forceinline__ unsigned int cvt_pk_bf16(float lo, float hi) {
    // gfx950 packed convert (R11-verified): D = {lo16: bf16(S0), hi16: bf16(S1)}
    unsigned int r;
    asm("v_cvt_pk_bf16_f32 %0, %1, %2" : "=v"(r) : "v"(lo), "v"(hi));
    return r;
}

// --- mfma wrapper: tolerate either V8bf16 or V8i16 builtin signature ---
template <typename A>
__device__ __forceinline__ auto mfma_try(A a, A b, f32x4 c, int)
    -> decltype(__builtin_amdgcn_mfma_f32_16x16x32_bf16(a, b, c, 0, 0, 0)) {
    return __builtin_amdgcn_mfma_f32_16x16x32_bf16(a, b, c, 0, 0, 0);
}
template <typename A>
__device__ __forceinline__ f32x4 mfma_try(A a, A b, f32x4 c, long) {
    return __builtin_amdgcn_mfma_f32_16x16x32_bf16(
        __builtin_bit_cast(short8, a), __builtin_bit_cast(short8, b), c, 0, 0, 0);
}
__device__ __forceinline__ f32x4 mfma_bf16(short8 a, short8 b, f32x4 c) {
    return mfma_try(__builtin_bit_cast(bf16x8, a), __builtin_bit_cast(bf16x8, b), c, 0);
}

__device__ __forceinline__ float tanh_pade(float x) {
    // clamped Pade(3,2) (R11/R13-verified): t(27+t^2)/(27+9t^2), |err|<=0.024
    const float t = fminf(fmaxf(x, -3.0f), 3.0f);
    const float s = t * t;
    return __fdividef(t * (27.0f + s), fmaf(9.0f, s, 27.0f));
}

__global__ __launch_bounds__(256, 4) void mixmodel_mfma21(
    const float* __restrict__ u,      // N*36
    const float* __restrict__ reg1,   // 6
    const float* __restrict__ reg2,   // 4
    const float* __restrict__ W1,     // 18*128
    const float* __restrict__ b1,     // 128
    const float* __restrict__ W2a,    // 128*54
    const float* __restrict__ b2a,    // 54
    const float* __restrict__ W2b,    // 128*72
    const float* __restrict__ b2b,    // 72
    float* __restrict__ out,          // N*36
    int N, int ntiles)
{
    __shared__ __align__(16) float          u_ext[32 * 40];   // 5120 B
    __shared__ __align__(16) unsigned short h_sh[32 * 136];   // 8704 B (verified layout)
    __shared__ __align__(16) unsigned short u_bf[32 * 32];    // 2048 B
    __shared__ __align__(16) float          c2s[32 * 148];    // 18944 B float, [row][8i+slot]
    // total = 34816 B -> 4 blocks/CU

    const int tid = threadIdx.x;
    const int wid = tid >> 6;
    const int l   = tid & 63;
    const int ln  = l & 15;
    const int lg  = l >> 4;
    const int nb  = wid * 32;

    reinterpret_cast<unsigned int*>(u_bf)[tid]       = 0u;
    reinterpret_cast<unsigned int*>(u_bf)[tid + 256] = 0u;
    __syncthreads();

    // ---- resident weight fragments (R10-verified data + maps): 40 VGPRs ----
    short8 b1f[2];
    short8 b2f[2][4];
    f32x4 bias1v[2];            // per-reg bias for swapped GEMM1
    float bias2[2];             // per-lane bias for unswapped GEMM2
    int c2idx[2];               // quad-interleaved in-row index (max 143)
#pragma unroll
    for (int t = 0; t < 2; ++t) {
        const int n = nb + t * 16 + ln;
        short8 v;
#pragma unroll
        for (int j = 0; j < 8; ++j) {
            const int k = lg * 8 + j;
            const float w = (k < 18) ? W1[k * 128 + n] : 0.0f;
            v[j] = (short)f2bf(w);
        }
        b1f[t] = v;
        bias1v[t] = *reinterpret_cast<const f32x4*>(&b1[nb + t * 16 + lg * 4]);
        bias2[t] = (n < 54) ? b2a[n] : (n < 126 ? b2b[n - 54] : 0.0f);
        if (n < 54)       c2idx[t] = (n / 3) * 8 + (n % 3);
        else if (n < 126) { const int m = n - 54; c2idx[t] = (m >> 2) * 8 + 4 + (m & 3); }
        else              c2idx[t] = 3;  // dump slot, never read
#pragma unroll
        for (int kk = 0; kk < 4; ++kk) {
            short8 w2;
#pragma unroll
            for (int j = 0; j < 8; ++j) {
                const int k = kk * 32 + lg * 8 + j;
                float w;
                if (n < 54)       w = W2a[k * 54 + n];
                else if (n < 126) w = W2b[k * 72 + (n - 54)];
                else              w = 0.0f;
                w2[j] = (short)f2bf(w);
            }
            b2f[t][kk] = w2;
        }
    }

    // ---- regression coefficients (wave-uniform -> SGPR) ----
    const float r10 = reg1[0], r11 = reg1[1], r12 = reg1[2];
    const float r13 = reg1[3], r14 = reg1[4], r15 = reg1[5];
    const float r20 = reg2[0], r21 = reg2[1], r22 = reg2[2], r23 = reg2[3];

    const float4* ug = reinterpret_cast<const float4*>(u);
    const long fmax4 = (long)N * 9 - 1;
    const int gs = gridDim.x;

    // ---- staging maps (R8-verified) ----
    const int row0 = tid / 9,          c0 = tid - row0 * 9;
    const int row1 = (256 + tid) / 9,  c1s = (256 + tid) - row1 * 9;
    const int hrow = (tid - 192) >> 1, hside = tid & 1;

    float4 pf0, pf1; float2 pfh;
    {
        const int r0 = blockIdx.x * 32;
        long g0 = (long)r0 * 9 + tid; if (g0 > fmax4) g0 = fmax4;
        pf0 = ug[g0];
        if (tid < 32) {
            long g1 = (long)r0 * 9 + 256 + tid; if (g1 > fmax4) g1 = fmax4;
            pf1 = ug[g1];
        }
        if (tid >= 192) {
            int rr = r0 + hrow; if (rr > N - 1) rr = N - 1;
            pfh = *reinterpret_cast<const float2*>(u + (size_t)rr * 36 + (hside ? 0 : 34));
        }
    }

    for (int tile = blockIdx.x; tile < ntiles; tile += gs) {
        // ---- stage u_ext / u_bf (cvt_pk, R11-verified); prefetch next ----
        {
            float* dst = &u_ext[row0 * 40 + 2 + c0 * 4];
            reinterpret_cast<float2*>(dst)[0] = make_float2(pf0.x, pf0.y);
            reinterpret_cast<float2*>(dst)[1] = make_float2(pf0.z, pf0.w);
            reinterpret_cast<unsigned int*>(u_bf)[row0 * 16 + c0] =
                cvt_pk_bf16(pf0.x, pf0.z);
            if (tid < 32) {
                float* dst1 = &u_ext[row1 * 40 + 2 + c1s * 4];
                reinterpret_cast<float2*>(dst1)[0] = make_float2(pf1.x, pf1.y);
                reinterpret_cast<float2*>(dst1)[1] = make_float2(pf1.z, pf1.w);
                reinterpret_cast<unsigned int*>(u_bf)[row1 * 16 + c1s] =
                    cvt_pk_bf16(pf1.x, pf1.z);
            }
            if (tid >= 192)
                *reinterpret_cast<float2*>(&u_ext[hrow * 40 + (hside ? 38 : 0)]) = pfh;

            if (tile + gs < ntiles) {
                const int r0n = (tile + gs) * 32;
                long g0 = (long)r0n * 9 + tid; if (g0 > fmax4) g0 = fmax4;
                pf0 = ug[g0];
                if (tid < 32) {
                    long g1 = (long)r0n * 9 + 256 + tid; if (g1 > fmax4) g1 = fmax4;
                    pf1 = ug[g1];
                }
                if (tid >= 192) {
                    int rr = r0n + hrow; if (rr > N - 1) rr = N - 1;
                    pfh = *reinterpret_cast<const float2*>(u + (size_t)rr * 36 + (hside ? 0 : 34));
                }
            }
        }
        __syncthreads();  // bar1: u ready

        // ---- GEMM1 SWAPPED: tanh_pade + cvt_pk -> 1 ds_write_b64 per (rb,t) ----
#pragma unroll
        for (int rb = 0; rb < 2; ++rb) {
            const short8 a1 = *reinterpret_cast<const short8*>(
                &u_bf[(rb * 16 + ln) * 32 + lg * 8]);
#pragma unroll
            for (int t = 0; t < 2; ++t) {
                const f32x4 h4 = mfma_bf16(b1f[t], a1, bias1v[t]);   // SWAPPED -> h^T
                const unsigned int p0 =
                    cvt_pk_bf16(tanh_pade(h4[0]), tanh_pade(h4[1]));
                const unsigned int p1 =
                    cvt_pk_bf16(tanh_pade(h4[2]), tanh_pade(h4[3]));
                *reinterpret_cast<uint2*>(
                    &h_sh[(rb * 16 + ln) * 136 + nb + t * 16 + lg * 4]) =
                    make_uint2(p0, p1);
            }
        }
        __syncthreads();  // bar2: h ready

        // ---- GEMM2 UNSWAPPED (R10-verified): b128 reads, 16 MFMA ----
        f32x4 acc2[2][2];
#pragma unroll
        for (int rb = 0; rb < 2; ++rb)
#pragma unroll
            for (int t = 0; t < 2; ++t) acc2[rb][t] = (f32x4)bias2[t];

#pragma unroll
        for (int rb = 0; rb < 2; ++rb) {
            const int arow = rb * 16 + ln;
#pragma unroll
            for (int kk = 0; kk < 4; ++kk) {
                const short8 a2 = *reinterpret_cast<const short8*>(
                    &h_sh[arow * 136 + kk * 32 + lg * 8]);
#pragma unroll
                for (int t = 0; t < 2; ++t)
                    acc2[rb][t] = mfma_bf16(a2, b2f[t][kk], acc2[rb][t]);
            }
        }

        // ---- C2 -> LDS float (R10-verified addressing, stride 148) ----
#pragma unroll
        for (int rb = 0; rb < 2; ++rb)
#pragma unroll
            for (int t = 0; t < 2; ++t)
#pragma unroll
                for (int r = 0; r < 4; ++r)
                    c2s[(rb * 16 + lg * 4 + r) * 148 + c2idx[t]] = acc2[rb][t][r];
        __syncthreads();  // bar3: c2 ready

        // ---- epilogue (R10-verified, stride 148) ----
        const int r0 = tile * 32;
#pragma unroll
        for (int s = 0; s < 3; ++s) {
            const int w = s * 256 + tid;
            if (w < 576) {
                const int row = w / 18;
                const int i   = w - row * 18;
                const int rg  = r0 + row;

                const float2 v0 = *reinterpret_cast<const float2*>(&u_ext[row * 40 + 2 * i]);
                const float2 v1 = *reinterpret_cast<const float2*>(&u_ext[row * 40 + 2 * i + 2]);
                const float2 v2 = *reinterpret_cast<const float2*>(&u_ext[row * 40 + 2 * i + 4]);
                const f32x4  q0 = *reinterpret_cast<const f32x4*>(&c2s[row * 148 + 8 * i]);
                const f32x4  q1 = *reinterpret_cast<const f32x4*>(&c2s[row * 148 + 8 * i + 4]);

                const float um2 = v0.x, uA = v0.y;
                const float ue  = v1.x, uo = v1.y;
                const float up2 = v2.x, uC = v2.y;

                const float oe = q0[0] + q0[1] * uA + q0[2] * uo;
                const float oo = q1[0] + q1[1] * uA + q1[2] * uo + q1[3] * uC;

                float re = r10;
                re = fmaf(r11, ue,       re);
                re = fmaf(r12, uo,       re);
                re = fmaf(r13, um2 * uA, re);
                re = fmaf(r14, uA * up2, re);
                re = fmaf(r15, ue * uo,  re);

                float ro = r20;
                ro = fmaf(r21, uo,       ro);
                ro = fmaf(r22, uA * ue,  ro);
                ro = fmaf(r23, ue * up2, ro);

                if (rg < N)
                    *reinterpret_cast<float2*>(out + (size_t)rg * 36 + 2 * i) =
                        make_float2(oe + re, oo + ro);
            }
        }
        __syncthreads();  // bar4: buffers free for next staging
    }
}

extern "C" void kernel_launch(void* const* d_in, const int* in_sizes, int n_in,
                              void* d_out, int out_size, void* d_ws, size_t ws_size,
                              hipStream_t stream) {
    // d_in order: t, u, reg1, reg2, W1, b1, W2a, b2a, W2b, b2b
    const float* u    = (const float*)d_in[1];
    const float* reg1 = (const float*)d_in[2];
    const float* reg2 = (const float*)d_in[3];
    const float* W1   = (const float*)d_in[4];
    const float* b1   = (const float*)d_in[5];
    const float* W2a  = (const float*)d_in[6];
    const float* b2a  = (const float*)d_in[7];
    const float* W2b  = (const float*)d_in[8];
    const float* b2b  = (const float*)d_in[9];
    float* out = (float*)d_out;

    const int N = in_sizes[1] / 36;
    const int ntiles = (N + 31) / 32;
    int grid = ntiles < 1024 ? ntiles : 1024;
    if (grid < 1) grid = 1;
    mixmodel_mfma21<<<grid, 256, 0, stream>>>(u, reg1, reg2, W1, b1,
                                              W2a, b2a, W2b, b2b, out, N, ntiles);
}